// Round 14
// baseline (241.710 us; speedup 1.0000x reference)
//
#include <hip/hip_runtime.h>
#include <hip/hip_fp8.h>
#include <stdint.h>
#include <math.h>

// cdist-attention. R14: de-confound R13. Scores K-loop reverted to R12's
// proven 112us config (GL2 staging, 8B-slot swizzle, depth-1); lsum fused
// WITHOUT atomics: per-block per-row partial sums -> lpart[z][jb][row]
// (plain stores, no contention, no zero-init); PV epilogue sums the 8
// partials and multiplies by reciprocal. zerok + atomicAdd + rowreduce<0>
// all gone. bf16 GEMMs / QK fp8 / VT / casts / rowreduce8 = R13 verbatim.

typedef __attribute__((ext_vector_type(8))) __bf16 bf16x8;
typedef __attribute__((ext_vector_type(4))) float f32x4;
typedef __attribute__((ext_vector_type(4))) unsigned int u32x4;
typedef __attribute__((ext_vector_type(2))) unsigned int u32x2;

__device__ __forceinline__ unsigned short f2b(float f) {
    unsigned u = __float_as_uint(f);
    unsigned r = 0x7fffu + ((u >> 16) & 1u);
    return (unsigned short)((u + r) >> 16);
}
__device__ __forceinline__ float b2f(unsigned short h) {
    return __uint_as_float(((unsigned)h) << 16);
}
__device__ __forceinline__ unsigned char f2f8(float f) {
    __hip_fp8_e4m3 t(f);
    return t.__x;
}
__device__ __forceinline__ float f8tof(unsigned char b) {
    int e = (b >> 3) & 15, m = b & 7;
    float v = e ? ldexpf(8.0f + m, e - 10) : ldexpf((float)m, -9);
    return (b & 0x80) ? -v : v;
}

__device__ __forceinline__ void wg_barrier() {
    asm volatile("" ::: "memory");
    __builtin_amdgcn_s_barrier();
    asm volatile("" ::: "memory");
}

__device__ __forceinline__ unsigned lds_off(const void* p) {
    return (unsigned)(uintptr_t)(const __attribute__((address_space(3))) char*)p;
}

__global__ __launch_bounds__(256) void castk(const float* __restrict__ src,
                                             unsigned short* __restrict__ dst, int n4) {
    int i = blockIdx.x * 256 + threadIdx.x;
    if (i >= n4) return;
    float4 v = ((const float4*)src)[i];
    ushort4 o;
    o.x = f2b(v.x); o.y = f2b(v.y); o.z = f2b(v.z); o.w = f2b(v.w);
    ((ushort4*)dst)[i] = o;
}

// row sum of squares over fp8-e4m3 rows (consistency with fp8 MFMA operands)
__global__ __launch_bounds__(256) void rowreduce8(const unsigned char* __restrict__ X,
                                                  int L, int rows, float* __restrict__ out) {
    int w = threadIdx.x >> 6, lane = threadIdx.x & 63;
    int row = blockIdx.x * 4 + w;
    if (row >= rows) return;
    const unsigned char* xr = X + (size_t)row * L;
    float s = 0.f;
    int passes = L >> 8;
    for (int p = 0; p < passes; ++p) {
        uchar4 u = *(const uchar4*)(xr + (p << 8) + lane * 4);
        float a = f8tof(u.x), b = f8tof(u.y), c = f8tof(u.z), d = f8tof(u.w);
        s += a * a + b * b + c * c + d * d;
    }
#pragma unroll
    for (int o = 32; o > 0; o >>= 1) s += __shfl_down(s, o);
    if (lane == 0) out[row] = s;
}

#define MF(A_, B_, C_) (C_) = __builtin_amdgcn_mfma_f32_16x16x32_bf16((A_), (B_), (C_), 0, 0, 0)
#define MF8(A_, B_, C_) (C_) = __builtin_amdgcn_mfma_f32_16x16x32_fp8_fp8((A_), (B_), (C_), 0, 0, 0)
#define DSR(dst_, a_, imm_) \
    asm volatile("ds_read_b128 %0, %1 offset:" #imm_ : "=v"(dst_) : "v"(a_))
#define DSR64(dst_, a_, imm_) \
    asm volatile("ds_read_b64 %0, %1 offset:" #imm_ : "=v"(dst_) : "v"(a_))
#define GL4(d_, p_) asm volatile("global_load_dwordx4 %0, %1, off" : "=v"(d_) : "v"(p_))
#define GL2(d_, p_) asm volatile("global_load_dwordx2 %0, %1, off" : "=v"(d_) : "v"(p_))
#define DSW(a_, imm_, d_) \
    asm volatile("ds_write_b128 %0, %1 offset:" #imm_ :: "v"(a_), "v"(d_) : "memory")
#define DSW64(a_, imm_, d_) \
    asm volatile("ds_write_b64 %0, %1 offset:" #imm_ :: "v"(a_), "v"(d_) : "memory")
#define LGKM(n_) asm volatile("s_waitcnt lgkmcnt(" #n_ ")" ::: "memory")
#define VMC0 asm volatile("s_waitcnt vmcnt(0)" ::: "memory")
#define SB0 __builtin_amdgcn_sched_barrier(0)

// ---------------- bf16 reg-staged GEMM (R12, verified) ----------------
#define LOADT(T_) do {                                                     \
    const size_t ko_ = (size_t)(T_) * 64;                                  \
    GL4(ra0, pa + ko_);             GL4(ra1, pa + lda64 + ko_);            \
    GL4(ra2, pa + 2 * lda64 + ko_); GL4(ra3, pa + 3 * lda64 + ko_);        \
    GL4(rb0, pb + ko_);             GL4(rb1, pb + ldb64 + ko_);            \
    GL4(rb2, pb + 2 * ldb64 + ko_); GL4(rb3, pb + 3 * ldb64 + ko_);        \
} while (0)
#define WRITET(WB_) do {                                                   \
    const unsigned wa_ = wA + (WB_), wb2_ = wB + (WB_);                    \
    DSW(wa_, 0, ra0);     DSW(wa_, 8192, ra1);                             \
    DSW(wa_, 16384, ra2); DSW(wa_, 24576, ra3);                            \
    DSW(wb2_, 0, rb0);     DSW(wb2_, 8192, rb1);                           \
    DSW(wb2_, 16384, rb2); DSW(wb2_, 24576, rb3);                          \
} while (0)

// EPI 0: bf16 out. EPI 2: f32 = acc * (1/sum8(lpart))[row]. EPI 3: fp8 out.
template <int EPI>
__global__ __launch_bounds__(512, 2) void gemm256(
    const unsigned short* __restrict__ A, int lda, long long sA,
    const unsigned short* __restrict__ B, int ldb, long long sB,
    void* __restrict__ Cv, int ldc, long long sC,
    int Kd, int perm,
    const float* __restrict__ aux1, int sAux1) {
    __shared__ __attribute__((aligned(128))) unsigned short As[2 * 256 * 64];
    __shared__ __attribute__((aligned(128))) unsigned short Bs[2 * 256 * 64];

    const int z = perm ? blockIdx.x : blockIdx.z;
    const int jb = perm ? blockIdx.y : blockIdx.x;
    const int ib = perm ? blockIdx.z : blockIdx.y;
    const unsigned short* __restrict__ Ab = A + (size_t)z * sA;
    const unsigned short* __restrict__ Bb = B + (size_t)z * sB;
    const int i0 = ib * 256, j0 = jb * 256;
    const int tid = threadIdx.x;
    const int w = tid >> 6, lane = tid & 63;
    const int wr = w >> 2, wc = w & 3;
    const int c16 = lane & 15, kq = lane >> 4;

    const int lr0 = tid >> 3;
    const int clog0 = (tid & 7) ^ (lr0 & 7);
    const unsigned short* pa = Ab + (size_t)(i0 + lr0) * lda + clog0 * 8;
    const unsigned short* pb = Bb + (size_t)(j0 + lr0) * ldb + clog0 * 8;
    const size_t lda64 = (size_t)64 * lda, ldb64 = (size_t)64 * ldb;

    const unsigned wA = lds_off(As) + (unsigned)tid * 16;
    const unsigned wB = lds_off(Bs) + (unsigned)tid * 16;

    const int swc = (kq ^ (c16 & 7)) << 4;
    const unsigned adrA0 = lds_off(As) + (unsigned)(wr * 128 + c16) * 128 + swc;
    const unsigned adrA0x = adrA0 ^ 64u;
    const unsigned adrB0 = lds_off(Bs) + (unsigned)(wc * 64 + c16) * 128 + swc;
    const unsigned adrB0x = adrB0 ^ 64u;

    f32x4 acc[8][4];
    const f32x4 zero = {0.f, 0.f, 0.f, 0.f};
#pragma unroll
    for (int i = 0; i < 8; ++i)
#pragma unroll
        for (int j = 0; j < 4; ++j) acc[i][j] = zero;

    u32x4 ra0, ra1, ra2, ra3, rb0, rb1, rb2, rb3;
    bf16x8 aL[4][2], aH[4][2], bF[4][2];

    const int nt = Kd >> 6;

    LOADT(0);
    VMC0;
    WRITET(0u);
    LOADT(1);
    LGKM(0);
    wg_barrier();

    for (int t = 0; t < nt; ++t) {
        const unsigned rb_ = (t & 1) ? 32768u : 0u;
        const unsigned wb_ = (t & 1) ? 0u : 32768u;
        const unsigned aA = adrA0 + rb_, aAx = adrA0x + rb_;
        const unsigned aB = adrB0 + rb_, aBx = adrB0x + rb_;
        DSR(aL[0][0], aA, 0);    DSR(aL[0][1], aAx, 0);
        DSR(aL[1][0], aA, 2048); DSR(aL[1][1], aAx, 2048);
        DSR(aL[2][0], aA, 4096); DSR(aL[2][1], aAx, 4096);
        DSR(aL[3][0], aA, 6144); DSR(aL[3][1], aAx, 6144);
        DSR(bF[0][0], aB, 0);    DSR(bF[0][1], aBx, 0);
        DSR(bF[1][0], aB, 2048); DSR(bF[1][1], aBx, 2048);
        DSR(bF[2][0], aB, 4096); DSR(bF[2][1], aBx, 4096);
        DSR(bF[3][0], aB, 6144); DSR(bF[3][1], aBx, 6144);
        if (t + 1 < nt) {
            VMC0;
            WRITET(wb_);
            if (t + 2 < nt) LOADT(t + 2);
            LGKM(8);
        } else {
            LGKM(0);
        }
        SB0;
        __builtin_amdgcn_s_setprio(1);
#pragma unroll
        for (int kk = 0; kk < 2; ++kk)
#pragma unroll
            for (int mi = 0; mi < 4; ++mi)
#pragma unroll
                for (int ni = 0; ni < 4; ++ni)
                    MF(aL[mi][kk], bF[ni][kk], acc[mi][ni]);
        __builtin_amdgcn_s_setprio(0);
        DSR(aH[0][0], aA, 8192);  DSR(aH[0][1], aAx, 8192);
        DSR(aH[1][0], aA, 10240); DSR(aH[1][1], aAx, 10240);
        DSR(aH[2][0], aA, 12288); DSR(aH[2][1], aAx, 12288);
        DSR(aH[3][0], aA, 14336); DSR(aH[3][1], aAx, 14336);
        LGKM(0); SB0;
        __builtin_amdgcn_s_setprio(1);
#pragma unroll
        for (int kk = 0; kk < 2; ++kk)
#pragma unroll
            for (int mi = 0; mi < 4; ++mi)
#pragma unroll
                for (int ni = 0; ni < 4; ++ni)
                    MF(aH[mi][kk], bF[ni][kk], acc[4 + mi][ni]);
        __builtin_amdgcn_s_setprio(0);
        wg_barrier();
    }
    // epilogues: per-wave LDS transpose -> coalesced 16B stores (R12)
    const int prow = kq * 4;
    if constexpr (EPI == 0) {
        unsigned short* C = (unsigned short*)Cv + (size_t)z * sC;
        unsigned short* sc = (unsigned short*)((char*)As + w * 8192);  // 16x72
        const int rr = lane >> 3, ch = lane & 7;
#pragma unroll
        for (int mi = 0; mi < 8; ++mi) {
#pragma unroll
            for (int ni = 0; ni < 4; ++ni)
#pragma unroll
                for (int r = 0; r < 4; ++r)
                    sc[(prow + r) * 72 + ni * 16 + c16] = f2b(acc[mi][ni][r]);
#pragma unroll
            for (int pass = 0; pass < 2; ++pass) {
                const int r2 = rr + 8 * pass;
                bf16x8 v = *(const bf16x8*)&sc[r2 * 72 + ch * 8];
                const int grow = i0 + wr * 128 + mi * 16 + r2;
                *(bf16x8*)&C[(size_t)grow * ldc + j0 + wc * 64 + ch * 8] = v;
            }
        }
    } else if constexpr (EPI == 3) {
        unsigned char* C = (unsigned char*)Cv + (size_t)z * sC;
        unsigned char* sc = (unsigned char*)As + w * 8192;  // 16x80 bytes
        const int rr = lane >> 2, ch = lane & 3;
#pragma unroll
        for (int mi = 0; mi < 8; ++mi) {
#pragma unroll
            for (int ni = 0; ni < 4; ++ni)
#pragma unroll
                for (int r = 0; r < 4; ++r)
                    sc[(prow + r) * 80 + ni * 16 + c16] = f2f8(acc[mi][ni][r]);
            u32x4 v = *(const u32x4*)&sc[rr * 80 + ch * 16];
            const int grow = i0 + wr * 128 + mi * 16 + rr;
            *(u32x4*)&C[(size_t)grow * ldc + j0 + wc * 64 + ch * 16] = v;
        }
    } else {
        // EPI 2 (PV): aux1 = lpart[z][8][2048]; l[row] = sum of 8 partials
        float* C = (float*)Cv + (size_t)z * sC;
        const float* lp = aux1 + (size_t)z * 8 * 2048;
        float* sc = (float*)((char*)As + w * 8192);  // 16x68 floats
        const int rr = lane >> 4, ch = lane & 15;
#pragma unroll
        for (int mi = 0; mi < 8; ++mi) {
            float linv[4];
#pragma unroll
            for (int r = 0; r < 4; ++r) {
                const int grow = i0 + wr * 128 + mi * 16 + prow + r;
                float s = 0.f;
#pragma unroll
                for (int j = 0; j < 8; ++j) s += lp[j * 2048 + grow];
                linv[r] = 1.0f / s;
            }
#pragma unroll
            for (int ni = 0; ni < 4; ++ni)
#pragma unroll
                for (int r = 0; r < 4; ++r)
                    sc[(prow + r) * 68 + ni * 16 + c16] = acc[mi][ni][r] * linv[r];
#pragma unroll
            for (int pass = 0; pass < 4; ++pass) {
                const int r2 = rr + 4 * pass;
                f32x4 v = *(const f32x4*)&sc[r2 * 68 + ch * 4];
                const int grow = i0 + wr * 128 + mi * 16 + r2;
                *(f32x4*)&C[(size_t)grow * ldc + j0 + wc * 64 + ch * 4] = v;
            }
        }
    }
}

// ---------------- fp8 scores GEMM (R12 K-loop: GL2, 8B-slot swizzle) ----------------
#define LOADT8(T_) do {                                                    \
    const size_t ko_ = (size_t)(T_) * 64;                                  \
    GL2(fa0, pa8 + ko_);              GL2(fa1, pa8 + lda64b + ko_);        \
    GL2(fa2, pa8 + 2 * lda64b + ko_); GL2(fa3, pa8 + 3 * lda64b + ko_);    \
    GL2(fb0, pb8 + ko_);              GL2(fb1, pb8 + ldb64b + ko_);        \
    GL2(fb2, pb8 + 2 * ldb64b + ko_); GL2(fb3, pb8 + 3 * ldb64b + ko_);    \
} while (0)
#define WRITET8(WB_) do {                                                  \
    const unsigned wa_ = wA8 + (WB_), wb2_ = wB8 + (WB_);                  \
    DSW64(wa_, 0, fa0);     DSW64(wa_, 4096, fa1);                         \
    DSW64(wa_, 8192, fa2);  DSW64(wa_, 12288, fa3);                        \
    DSW64(wb2_, 0, fb0);    DSW64(wb2_, 4096, fb1);                        \
    DSW64(wb2_, 8192, fb2); DSW64(wb2_, 12288, fb3);                       \
} while (0)

__global__ __launch_bounds__(512, 2) void gemm256f8(
    const unsigned char* __restrict__ A, int lda, long long sA,
    const unsigned char* __restrict__ B, int ldb, long long sB,
    unsigned short* __restrict__ Cq, int ldc, long long sC,
    int Kd,
    const float* __restrict__ q2a, int sQ2,
    const float* __restrict__ k2a, int sK2,
    float* __restrict__ lpart, float invs) {
    __shared__ __attribute__((aligned(128))) unsigned char As8[2 * 256 * 64];
    __shared__ __attribute__((aligned(128))) unsigned char Bs8[2 * 256 * 64];

    const int z = blockIdx.x;        // XCD i owns batch i
    const int jb = blockIdx.y, ib = blockIdx.z;
    const unsigned char* __restrict__ Ab = A + (size_t)z * sA;
    const unsigned char* __restrict__ Bb = B + (size_t)z * sB;
    const int i0 = ib * 256, j0 = jb * 256;
    const int tid = threadIdx.x;
    const int w = tid >> 6, lane = tid & 63;
    const int wr = w >> 2, wc = w & 3;
    const int c16 = lane & 15, kq = lane >> 4;

    const int lr0 = tid >> 3;
    const int slog = (tid & 7) ^ (lr0 & 7);
    const unsigned char* pa8 = Ab + (size_t)(i0 + lr0) * lda + slog * 8;
    const unsigned char* pb8 = Bb + (size_t)(j0 + lr0) * ldb + slog * 8;
    const size_t lda64b = (size_t)64 * lda, ldb64b = (size_t)64 * ldb;

    const unsigned wA8 = lds_off(As8) + (unsigned)tid * 8;
    const unsigned wB8 = lds_off(Bs8) + (unsigned)tid * 8;

    const int sw8 = (kq ^ (c16 & 7)) << 3;
    const unsigned adrA0 = lds_off(As8) + (unsigned)(wr * 128 + c16) * 64 + sw8;
    const unsigned adrA0x = adrA0 ^ 32u;
    const unsigned adrB0 = lds_off(Bs8) + (unsigned)(wc * 64 + c16) * 64 + sw8;
    const unsigned adrB0x = adrB0 ^ 32u;

    f32x4 acc[8][4];
    const f32x4 zero = {0.f, 0.f, 0.f, 0.f};
#pragma unroll
    for (int i = 0; i < 8; ++i)
#pragma unroll
        for (int j = 0; j < 4; ++j) acc[i][j] = zero;

    u32x2 fa0, fa1, fa2, fa3, fb0, fb1, fb2, fb3;
    long aL[4][2], aH[4][2], bF[4][2];

    const int nt = Kd >> 6;

    LOADT8(0);
    VMC0;
    WRITET8(0u);
    LOADT8(1);
    LGKM(0);
    wg_barrier();

    for (int t = 0; t < nt; ++t) {
        const unsigned rb_ = (t & 1) ? 16384u : 0u;
        const unsigned wb_ = (t & 1) ? 0u : 16384u;
        const unsigned aA = adrA0 + rb_, aAx = adrA0x + rb_;
        const unsigned aB = adrB0 + rb_, aBx = adrB0x + rb_;
        DSR64(aL[0][0], aA, 0);    DSR64(aL[0][1], aAx, 0);
        DSR64(aL[1][0], aA, 1024); DSR64(aL[1][1], aAx, 1024);
        DSR64(aL[2][0], aA, 2048); DSR64(aL[2][1], aAx, 2048);
        DSR64(aL[3][0], aA, 3072); DSR64(aL[3][1], aAx, 3072);
        DSR64(bF[0][0], aB, 0);    DSR64(bF[0][1], aBx, 0);
        DSR64(bF[1][0], aB, 1024); DSR64(bF[1][1], aBx, 1024);
        DSR64(bF[2][0], aB, 2048); DSR64(bF[2][1], aBx, 2048);
        DSR64(bF[3][0], aB, 3072); DSR64(bF[3][1], aBx, 3072);
        if (t + 1 < nt) {
            VMC0;
            WRITET8(wb_);
            if (t + 2 < nt) LOADT8(t + 2);
            LGKM(8);
        } else {
            LGKM(0);
        }
        SB0;
        __builtin_amdgcn_s_setprio(1);
#pragma unroll
        for (int kk = 0; kk < 2; ++kk)
#pragma unroll
            for (int mi = 0; mi < 4; ++mi)
#pragma unroll
                for (int ni = 0; ni < 4; ++ni)
                    MF8(aL[mi][kk], bF[ni][kk], acc[mi][ni]);
        __builtin_amdgcn_s_setprio(0);
        DSR64(aH[0][0], aA, 4096); DSR64(aH[0][1], aAx, 4096);
        DSR64(aH[1][0], aA, 5120); DSR64(aH[1][1], aAx, 5120);
        DSR64(aH[2][0], aA, 6144); DSR64(aH[2][1], aAx, 6144);
        DSR64(aH[3][0], aA, 7168); DSR64(aH[3][1], aAx, 7168);
        LGKM(0); SB0;
        __builtin_amdgcn_s_setprio(1);
#pragma unroll
        for (int kk = 0; kk < 2; ++kk)
#pragma unroll
            for (int mi = 0; mi < 4; ++mi)
#pragma unroll
                for (int ni = 0; ni < 4; ++ni)
                    MF8(aH[mi][kk], bF[ni][kk], acc[4 + mi][ni]);
        __builtin_amdgcn_s_setprio(0);
        wg_barrier();
    }

    // epilogue: E = exp(sqrt(max(q2+k2-2*acc,0))*invs) -> bf16 coalesced
    // + per-block row-sums: shfl over c16, 4-wave combine in dead Bs8,
    //   ONE plain store per (block,row) -> lpart[z][jb][row]. No atomics.
    unsigned short* C = Cq + (size_t)z * sC;
    const float* q2b = q2a + (size_t)z * sQ2;
    const float* k2b = k2a + (size_t)z * sK2;
    unsigned short* sc = (unsigned short*)(As8 + w * 4096);  // 16x72 shorts
    float* lred = (float*)Bs8;  // [2 wr][4 wc][128 rows] = 4 KiB
    const int prow = kq * 4;
    const int rr = lane >> 3, ch = lane & 7;
#pragma unroll
    for (int mi = 0; mi < 8; ++mi) {
        float ev[4][4];
#pragma unroll
        for (int ni = 0; ni < 4; ++ni) {
            const int col = j0 + wc * 64 + ni * 16 + c16;
            const float k2v = k2b[col];
#pragma unroll
            for (int r = 0; r < 4; ++r) {
                const int grow = i0 + wr * 128 + mi * 16 + prow + r;
                float d2 = q2b[grow] + k2v - 2.0f * acc[mi][ni][r];
                ev[ni][r] = __expf(sqrtf(fmaxf(d2, 0.f)) * invs);
            }
        }
#pragma unroll
        for (int r = 0; r < 4; ++r) {
            float s = ev[0][r] + ev[1][r] + ev[2][r] + ev[3][r];
#pragma unroll
            for (int m = 1; m < 16; m <<= 1) s += __shfl_xor(s, m);
            if (c16 == 0)
                lred[(wr * 4 + wc) * 128 + mi * 16 + prow + r] = s;
        }
#pragma unroll
        for (int ni = 0; ni < 4; ++ni)
#pragma unroll
            for (int r = 0; r < 4; ++r)
                sc[(prow + r) * 72 + ni * 16 + c16] = f2b(ev[ni][r]);
#pragma unroll
        for (int pass = 0; pass < 2; ++pass) {
            const int r2 = rr + 8 * pass;
            bf16x8 v = *(const bf16x8*)&sc[r2 * 72 + ch * 8];
            const int grow = i0 + wr * 128 + mi * 16 + r2;
            *(bf16x8*)&C[(size_t)grow * ldc + j0 + wc * 64 + ch * 8] = v;
        }
    }
    LGKM(0);
    wg_barrier();
    if (wc == 0) {  // one wave per wr half: combine 4 col-waves, store lpart
        float* lrow = lpart + ((size_t)z * 8 + jb) * 2048 + i0 + wr * 128;
#pragma unroll
        for (int h = 0; h < 2; ++h) {
            const int row = lane + h * 64;
            float s = lred[(wr * 4 + 0) * 128 + row] + lred[(wr * 4 + 1) * 128 + row] +
                      lred[(wr * 4 + 2) * 128 + row] + lred[(wr * 4 + 3) * 128 + row];
            lrow[row] = s;
        }
    }
}

extern "C" void kernel_launch(void* const* d_in, const int* in_sizes, int n_in,
                              void* d_out, int out_size, void* d_ws, size_t ws_size,
                              hipStream_t stream) {
    const float* x = (const float*)d_in[0];
    const float* Wq = (const float*)d_in[1];
    const float* Wk = (const float*)d_in[2];
    const float* Wv = (const float*)d_in[3];
    const int Bz = 8, S = 2048, D = 768, F = 768;
    const int BS = Bz * S;  // 16384

    const size_t szX = (size_t)BS * D * 2;
    const size_t szW = (size_t)F * D * 2;
    const size_t szQ8 = (size_t)BS * F;
    const size_t szE = (size_t)Bz * S * S * 2;

    char* p = (char*)d_ws;
    unsigned short* xb = (unsigned short*)p;  p += szX;
    unsigned short* Wqb = (unsigned short*)p; p += szW;
    unsigned short* Wkb = (unsigned short*)p; p += szW;
    unsigned short* Wvb = (unsigned short*)p; p += szW;
    unsigned char* Q8 = (unsigned char*)p;    p += szQ8;
    unsigned char* K8 = (unsigned char*)p;    p += szQ8;
    unsigned short* VT = (unsigned short*)p;  p += szX;   // [F][BS]
    unsigned short* E = (unsigned short*)p;   p += szE;   // [Bz][S][S]
    float* q2 = (float*)p;    p += (size_t)BS * 4;
    float* k2 = (float*)p;    p += (size_t)BS * 4;
    float* lpart = (float*)p; p += (size_t)Bz * 8 * 2048 * 4;  // [z][jb][row]
    if ((size_t)(p - (char*)d_ws) > ws_size) return;  // ~147 MiB scratch required

    const float invs = 1.0f / sqrtf(768.0f);

    // 1) casts
    castk<<<(BS * D / 4 + 255) / 256, 256, 0, stream>>>(x, xb, BS * D / 4);
    castk<<<(F * D / 4 + 255) / 256, 256, 0, stream>>>(Wq, Wqb, F * D / 4);
    castk<<<(F * D / 4 + 255) / 256, 256, 0, stream>>>(Wk, Wkb, F * D / 4);
    castk<<<(F * D / 4 + 255) / 256, 256, 0, stream>>>(Wv, Wvb, F * D / 4);

    // 2) Q8,K8 = e4m3(x . W^T)  (z=0 -> Wq->Q8, z=1 -> Wk->K8)
    gemm256<3><<<dim3(F / 256, BS / 256, 2), 512, 0, stream>>>(
        xb, D, 0,
        Wqb, D, (long long)F * D,
        Q8, F, (long long)BS * F,
        D, 0, nullptr, 0);

    //    V^T = Wv . x^T   -> VT[f][s] (bf16)
    gemm256<0><<<dim3(BS / 256, F / 256, 1), 512, 0, stream>>>(
        Wvb, D, 0,
        xb, D, 0,
        VT, BS, 0,
        D, 0, nullptr, 0);

    // 3) q2,k2 from the fp8-rounded values
    rowreduce8<<<BS / 4, 256, 0, stream>>>(Q8, F, BS, q2);
    rowreduce8<<<BS / 4, 256, 0, stream>>>(K8, F, BS, k2);

    // 4) E + per-block lpart; x=batch -> XCD-pinned
    gemm256f8<<<dim3(Bz, S / 256, S / 256), 512, 0, stream>>>(
        Q8, F, (long long)S * F,
        K8, F, (long long)S * F,
        E, S, (long long)S * S,
        F, q2, S, k2, S, lpart, invs);

    // 5) out = (E . V) / sum8(lpart); x=batch -> XCD reads the E_z it wrote
    gemm256<2><<<dim3(Bz, F / 256, S / 256), 512, 0, stream>>>(
        E, S, (long long)S * S,
        VT, BS, (long long)S,
        d_out, F, (long long)S * F,
        S, 1, lpart, 0);
}